// Round 1
// baseline (3850.372 us; speedup 1.0000x reference)
//
#include <hip/hip_runtime.h>
#include <cstddef>

// Problem constants (match reference)
constexpr int T  = 16;
constexpr int N  = 10000;
constexpr int M  = 2048;
constexpr int F  = 256;    // F_IN = F1 = F2
constexpr int H  = 256;
constexpr int G4 = 1024;   // 4*H

// ---------------- generic tiled fp32 GEMM ----------------
// C[M,N] = (relu?)(A[M,K] @ B) ; B is [K,N] (TRANSB=false) or [N,K] (TRANSB=true)
// batched over blockIdx.z with element strides sA/sB/sC.
template<bool TRANSB, bool RELU>
__global__ __launch_bounds__(256)
void gemm_f32(const float* __restrict__ Ag, long long sA,
              const float* __restrict__ Bg, long long sB,
              float* __restrict__ Cg, long long sC,
              int Mm, int Nn, int Kk)
{
    const float* A = Ag + (size_t)blockIdx.z * sA;
    const float* B = Bg + (size_t)blockIdx.z * sB;
    float*       C = Cg + (size_t)blockIdx.z * sC;

    __shared__ float As[16][64];
    __shared__ float Bs[16][65];

    const int tid = threadIdx.x;
    const int tx = tid & 15, ty = tid >> 4;
    const int m0 = blockIdx.y * 64, n0 = blockIdx.x * 64;

    float acc[4][4] = {};

    for (int k0 = 0; k0 < Kk; k0 += 16) {
        { // A tile: 64 rows x 16 k
            int r = tid >> 2;
            int c = (tid & 3) << 2;
            int m = m0 + r;
            float4 v = make_float4(0.f, 0.f, 0.f, 0.f);
            if (m < Mm) v = *(const float4*)&A[(size_t)m * Kk + k0 + c];
            As[c + 0][r] = v.x; As[c + 1][r] = v.y;
            As[c + 2][r] = v.z; As[c + 3][r] = v.w;
        }
        if (!TRANSB) { // B tile: 16 k x 64 n
            int r = tid >> 4;
            int c = (tid & 15) << 2;
            float4 v = *(const float4*)&B[(size_t)(k0 + r) * Nn + n0 + c];
            Bs[r][c + 0] = v.x; Bs[r][c + 1] = v.y;
            Bs[r][c + 2] = v.z; Bs[r][c + 3] = v.w;
        } else {       // B is [N,K]: Bs[k][n] = B[n0+n][k0+k]
            int n = tid >> 2;
            int c = (tid & 3) << 2;
            float4 v = make_float4(0.f, 0.f, 0.f, 0.f);
            if (n0 + n < Nn) v = *(const float4*)&B[(size_t)(n0 + n) * Kk + k0 + c];
            Bs[c + 0][n] = v.x; Bs[c + 1][n] = v.y;
            Bs[c + 2][n] = v.z; Bs[c + 3][n] = v.w;
        }
        __syncthreads();

        #pragma unroll
        for (int kk = 0; kk < 16; ++kk) {
            float a[4], b[4];
            #pragma unroll
            for (int i = 0; i < 4; ++i) a[i] = As[kk][ty + (i << 4)];
            #pragma unroll
            for (int j = 0; j < 4; ++j) b[j] = Bs[kk][tx + (j << 4)];
            #pragma unroll
            for (int i = 0; i < 4; ++i)
                #pragma unroll
                for (int j = 0; j < 4; ++j)
                    acc[i][j] = fmaf(a[i], b[j], acc[i][j]);
        }
        __syncthreads();
    }

    #pragma unroll
    for (int i = 0; i < 4; ++i) {
        int m = m0 + ty + (i << 4);
        if (m >= Mm) continue;
        #pragma unroll
        for (int j = 0; j < 4; ++j) {
            int n = n0 + tx + (j << 4);
            float v = acc[i][j];
            if (RELU) v = fmaxf(v, 0.f);
            C[(size_t)m * Nn + n] = v;
        }
    }
}

// ---------------- gather masked rows: G[t][p] = Y0[mask[t][p]] ----------------
__global__ void gather_rows(const float* __restrict__ src, const int* __restrict__ mask,
                            float* __restrict__ dst)
{
    int t = blockIdx.y;
    int p = blockIdx.x;
    int row = mask[t * M + p];
    const float4* s = (const float4*)&src[(size_t)row * F];
    float4* d = (float4*)&dst[((size_t)t * M + p) * F];
    for (int j = threadIdx.x; j < F / 4; j += blockDim.x) d[j] = s[j];
}

// ---------------- inverse mask map: inv[t][node] = position or -1 ----------------
__global__ void build_inv(const int* __restrict__ mask, int* __restrict__ inv)
{
    int i = blockIdx.x * blockDim.x + threadIdx.x;
    if (i >= T * M) return;
    int t = i / M;
    inv[(size_t)t * N + mask[i]] = i % M;
}

// ---------------- LSTM cell elementwise update ----------------
__global__ __launch_bounds__(256)
void lstm_cell(const float* __restrict__ U, const float* __restrict__ V,
               const float* __restrict__ ztmp, const int* __restrict__ invt,
               const float* __restrict__ b_ih, const float* __restrict__ b_hh,
               float* __restrict__ cbuf, float* __restrict__ h)
{
    int idx = blockIdx.x * blockDim.x + threadIdx.x;
    if (idx >= N * H) return;
    int node = idx >> 8, j = idx & 255;
    int p = invt[node];
    const float* base = (p >= 0) ? (V + (size_t)p * G4) : (U + (size_t)node * G4);
    const float* zt = ztmp + (size_t)node * G4;

    float zi = base[j      ] + zt[j      ] + b_ih[j      ] + b_hh[j      ];
    float zf = base[j + 256] + zt[j + 256] + b_ih[j + 256] + b_hh[j + 256];
    float zg = base[j + 512] + zt[j + 512] + b_ih[j + 512] + b_hh[j + 512];
    float zo = base[j + 768] + zt[j + 768] + b_ih[j + 768] + b_hh[j + 768];

    float ig = 1.f / (1.f + expf(-zi));
    float fg = 1.f / (1.f + expf(-zf));
    float gg = tanhf(zg);
    float og = 1.f / (1.f + expf(-zo));

    float c = fg * cbuf[idx] + ig * gg;
    cbuf[idx] = c;
    h[idx] = og * tanhf(c);
}

extern "C" void kernel_launch(void* const* d_in, const int* in_sizes, int n_in,
                              void* d_out, int out_size, void* d_ws, size_t ws_size,
                              hipStream_t stream)
{
    const float* A_all = (const float*)d_in[0];   // [T, M, M]
    const float* nf    = (const float*)d_in[1];   // [N, F]
    const int*   mask  = (const int*)  d_in[2];   // [T, M]
    const float* w0    = (const float*)d_in[3];   // [F, F]
    const float* w1    = (const float*)d_in[4];   // [F, F]
    const float* W_ih  = (const float*)d_in[5];   // [4H, F]
    const float* W_hh  = (const float*)d_in[6];   // [4H, H]
    const float* b_ih  = (const float*)d_in[7];   // [4H]
    const float* b_hh  = (const float*)d_in[8];   // [4H]
    float* h = (float*)d_out;                     // [N, H] final hidden = output

    // Workspace layout (floats). Total ~189 MB.
    float* ws = (float*)d_ws;
    size_t off = 0;
    float* Y0 = ws + off; off += (size_t)N * F;       // node_feats @ w0
    float* Y1 = ws + off; off += (size_t)N * F;       // Y0 @ w1
    float* U  = ws + off; off += (size_t)N * G4;      // Y1 @ W_ih^T
    float* Gb = ws + off; off += (size_t)T * M * F;   // gathered rows / Z2
    float* Zb = ws + off; off += (size_t)T * M * F;   // Z1 / Z3
    float* V  = ws + off; off += (size_t)M * G4;      // Z3_t @ W_ih^T (per step)
    float* ZT = ws + off; off += (size_t)N * G4;      // h @ W_hh^T (per step)
    float* Cb = ws + off; off += (size_t)N * H;       // LSTM cell state
    int*   inv = (int*)(ws + off);                    // [T, N] position-or--1

    // init: h0 = c0 = 0 ; inv = -1 (0xFF bytes)
    hipMemsetAsync(h,  0, (size_t)N * H * sizeof(float), stream);
    hipMemsetAsync(Cb, 0, (size_t)N * H * sizeof(float), stream);
    hipMemsetAsync(inv, 0xFF, (size_t)T * N * sizeof(int), stream);
    build_inv<<<dim3((T * M + 255) / 256), 256, 0, stream>>>(mask, inv);

    const dim3 blk(256);
    const int MY = (N + 63) / 64;   // 157 row-blocks for N=10000

    // Y0 = nf @ w0 ; Y1 = Y0 @ w1 ; U = Y1 @ W_ih^T
    gemm_f32<false, false><<<dim3(F / 64, MY, 1), blk, 0, stream>>>(nf, 0, w0, 0, Y0, 0, N, F, F);
    gemm_f32<false, false><<<dim3(F / 64, MY, 1), blk, 0, stream>>>(Y0, 0, w1, 0, Y1, 0, N, F, F);
    gemm_f32<true,  false><<<dim3(G4 / 64, MY, 1), blk, 0, stream>>>(Y1, 0, W_ih, 0, U, 0, N, G4, F);

    // G[t] = Y0[mask[t]]   (batched over t)
    gather_rows<<<dim3(M, T), 64, 0, stream>>>(Y0, mask, Gb);

    const long long sAmm = (long long)M * M;
    const long long sMF  = (long long)M * F;
    // Z1 = relu(A_t @ G_t)          -> Zb
    gemm_f32<false, true ><<<dim3(F / 64, M / 64, T), blk, 0, stream>>>(A_all, sAmm, Gb, sMF, Zb, sMF, M, F, M);
    // Z2 = Z1 @ w1                  -> Gb
    gemm_f32<false, false><<<dim3(F / 64, M / 64, T), blk, 0, stream>>>(Zb, sMF, w1, 0, Gb, sMF, M, F, F);
    // Z3 = relu(A_t @ Z2)           -> Zb
    gemm_f32<false, true ><<<dim3(F / 64, M / 64, T), blk, 0, stream>>>(A_all, sAmm, Gb, sMF, Zb, sMF, M, F, M);

    // Sequential LSTM over T steps
    for (int t = 0; t < T; ++t) {
        const float* Z3t = Zb + (size_t)t * M * F;
        // V = Z3_t @ W_ih^T   (masked-row input projection)
        gemm_f32<true, false><<<dim3(G4 / 64, M / 64, 1), blk, 0, stream>>>(Z3t, 0, W_ih, 0, V, 0, M, G4, F);
        // ZT = h @ W_hh^T     (recurrent projection — sequential dependency)
        gemm_f32<true, false><<<dim3(G4 / 64, MY, 1), blk, 0, stream>>>(h, 0, W_hh, 0, ZT, 0, N, G4, F);
        // gate math + state update
        lstm_cell<<<dim3((N * H + 255) / 256), 256, 0, stream>>>(
            U, V, ZT, inv + (size_t)t * N, b_ih, b_hh, Cb, h);
    }
}

// Round 2
// 816.265 us; speedup vs baseline: 4.7171x; 4.7171x over previous
//
#include <hip/hip_runtime.h>
#include <cstdint>
#include <cstddef>

#pragma clang diagnostic ignored "-Waddress-space-conversion"

constexpr int T  = 16;
constexpr int N  = 10000;
constexpr int M  = 2048;
constexpr int F  = 256;
constexpr int H  = 256;
constexpr int G4 = 1024;
constexpr int NP = 10112;   // N padded to multiple of 128

typedef _Float16 f16;
using half8  = __attribute__((ext_vector_type(8))) f16;
using half4  = __attribute__((ext_vector_type(4))) f16;
using half2v = __attribute__((ext_vector_type(2))) f16;
using f32x4  = __attribute__((ext_vector_type(4))) float;

typedef __attribute__((address_space(1))) const void gas_t;
typedef __attribute__((address_space(3))) void las_t;

__device__ __forceinline__ void gl_lds16(const f16* g, f16* l) {
    __builtin_amdgcn_global_load_lds((gas_t*)g, (las_t*)l, 16, 0, 0);
}

// ---------------------------------------------------------------------------
// C[m][n] (+relu) = A[m][k] * B[n][k]   (both operands k-contiguous)
// A: f32 (AF32, reg-staged+converted) or f16 (global_load_lds).
// OMODE: 0 = f32 row-major, 1 = f16 row-major, 2 = f16 transposed (C^T [Nn][ldct])
// Batched over blockIdx.z with element strides sA/sB/sC. M-tile=128, N-tile=128, BK=32.
// ---------------------------------------------------------------------------
template<bool AF32, bool RELU, int OMODE>
__global__ __launch_bounds__(256, 2)
void gemm16(const void* __restrict__ Ag, long long sA,
            const f16*  __restrict__ Bg, long long sB,
            void*       __restrict__ Cg, long long sC,
            int Kk, int Nn, int Mvalid, int ldct)
{
    __shared__ f16 Als[2][128 * 32];
    __shared__ f16 Bls[2][128 * 32];

    const int tid  = threadIdx.x;
    const int lane = tid & 63;
    const int w    = tid >> 6;        // wave 0..3
    const int wm   = w >> 1, wn = w & 1;
    const int m0   = blockIdx.y * 128, n0 = blockIdx.x * 128;
    const int z    = blockIdx.z;

    const f16* Bt = Bg + (size_t)z * sB;
    const int srow = lane >> 2;        // 0..15
    const int scol = (lane & 3) * 8;   // f16 column offset within 32

    f32x4 acc[4][4] = {};

    auto stage = [&](int buf, int kt) {
        const int k0 = kt * 32;
        #pragma unroll
        for (int c = 0; c < 2; ++c) {
            const int brow = w * 32 + c * 16;
            gl_lds16(Bt + (size_t)(n0 + brow + srow) * Kk + k0 + scol,
                     &Bls[buf][brow * 32]);
        }
        if constexpr (AF32) {
            const float* Af = (const float*)Ag + (size_t)z * sA;
            #pragma unroll
            for (int p = 0; p < 4; ++p) {
                const int flat = p * 1024 + tid * 4;
                const int r = flat >> 5, cc = flat & 31;
                float4 v = *(const float4*)&Af[(size_t)(m0 + r) * Kk + k0 + cc];
                half4 hv = { (f16)v.x, (f16)v.y, (f16)v.z, (f16)v.w };
                *(half4*)&Als[buf][r * 32 + cc] = hv;
            }
        } else {
            const f16* Af = (const f16*)Ag + (size_t)z * sA;
            #pragma unroll
            for (int c = 0; c < 2; ++c) {
                const int arow = w * 32 + c * 16;
                gl_lds16(Af + (size_t)(m0 + arow + srow) * Kk + k0 + scol,
                         &Als[buf][arow * 32]);
            }
        }
    };

    const int nk = Kk >> 5;
    stage(0, 0);
    int cur = 0;
    const int fr = lane & 15, fg = lane >> 4;

    for (int kt = 0; kt < nk; ++kt) {
        __syncthreads();                       // drains vmcnt+lgkmcnt: buf `cur` ready
        if (kt + 1 < nk) stage(cur ^ 1, kt + 1);

        half8 a[4], b[4];
        #pragma unroll
        for (int i = 0; i < 4; ++i)
            a[i] = *(const half8*)&Als[cur][(wm * 64 + i * 16 + fr) * 32 + fg * 8];
        #pragma unroll
        for (int j = 0; j < 4; ++j)
            b[j] = *(const half8*)&Bls[cur][(wn * 64 + j * 16 + fr) * 32 + fg * 8];
        #pragma unroll
        for (int i = 0; i < 4; ++i)
            #pragma unroll
            for (int j = 0; j < 4; ++j)
                acc[i][j] = __builtin_amdgcn_mfma_f32_16x16x32_f16(a[i], b[j], acc[i][j], 0, 0, 0);
        cur ^= 1;
    }

    #pragma unroll
    for (int i = 0; i < 4; ++i) {
        const int gmb = m0 + wm * 64 + i * 16 + fg * 4;
        #pragma unroll
        for (int j = 0; j < 4; ++j) {
            const int gn = n0 + wn * 64 + j * 16 + fr;
            f32x4 v = acc[i][j];
            if (RELU) {
                v[0] = fmaxf(v[0], 0.f); v[1] = fmaxf(v[1], 0.f);
                v[2] = fmaxf(v[2], 0.f); v[3] = fmaxf(v[3], 0.f);
            }
            if constexpr (OMODE == 0) {
                float* Cf = (float*)Cg + (size_t)z * sC;
                #pragma unroll
                for (int r = 0; r < 4; ++r)
                    if (gmb + r < Mvalid) Cf[(size_t)(gmb + r) * Nn + gn] = v[r];
            } else if constexpr (OMODE == 1) {
                f16* Ch = (f16*)Cg + (size_t)z * sC;
                #pragma unroll
                for (int r = 0; r < 4; ++r)
                    if (gmb + r < Mvalid) Ch[(size_t)(gmb + r) * Nn + gn] = (f16)v[r];
            } else {
                f16* Ct = (f16*)Cg + (size_t)z * sC;
                half4 hv = { (f16)v[0], (f16)v[1], (f16)v[2], (f16)v[3] };
                if (gmb + 3 < Mvalid) *(half4*)&Ct[(size_t)gn * ldct + gmb] = hv;
            }
        }
    }
}

// GT[t][f][p] = Y0h[mask[t][p]][f]  (gather rows + transpose, f16)
__global__ __launch_bounds__(256)
void gather_T(const f16* __restrict__ Y0h, const int* __restrict__ mask,
              f16* __restrict__ GT)
{
    __shared__ f16 tile[64][F + 8];
    const int t = blockIdx.y, p0 = blockIdx.x * 64;
    const int tid = threadIdx.x;
    const int pr = tid >> 2;
    const int fc = (tid & 3) * 8;

    const int row = mask[t * M + p0 + pr];
    const f16* src = Y0h + (size_t)row * F;
    #pragma unroll
    for (int it = 0; it < 8; ++it) {
        const int f = it * 32 + fc;
        *(half8*)&tile[pr][f] = *(const half8*)&src[f];
    }
    __syncthreads();

    f16* dst = GT + ((size_t)t * F + tid) * M + p0;
    #pragma unroll
    for (int pc = 0; pc < 64; pc += 8) {
        half8 v;
        #pragma unroll
        for (int r = 0; r < 8; ++r) v[r] = tile[pc + r][tid];
        *(half8*)&dst[pc] = v;
    }
}

__global__ void cvt_f16(const float* __restrict__ s, f16* __restrict__ d, long long n)
{
    long long base = ((long long)blockIdx.x * blockDim.x + threadIdx.x) * 4;
    if (base + 3 < n) {
        float4 v = *(const float4*)&s[base];
        half4 hv = { (f16)v.x, (f16)v.y, (f16)v.z, (f16)v.w };
        *(half4*)&d[base] = hv;
    } else {
        for (long long k = base; k < n; ++k) d[k] = (f16)s[k];
    }
}

// d[c][r] = s[r][c]  (transpose + convert, small matrices)
__global__ void cvtT_f16(const float* __restrict__ s, f16* __restrict__ d, int R, int C)
{
    int i = blockIdx.x * 256 + threadIdx.x;
    if (i >= R * C) return;
    int r = i % R, c = i / R;
    d[(size_t)c * R + r] = (f16)s[(size_t)r * C + c];
}

__global__ void build_inv(const int* __restrict__ mask, int* __restrict__ inv)
{
    int i = blockIdx.x * blockDim.x + threadIdx.x;
    if (i >= T * M) return;
    int t = i / M;
    inv[(size_t)t * N + mask[i]] = i % M;
}

__global__ __launch_bounds__(256)
void lstm_cell(const f16* __restrict__ U, const f16* __restrict__ V,
               const f16* __restrict__ Zr, const int* __restrict__ invt,
               const float* __restrict__ b_ih, const float* __restrict__ b_hh,
               float* __restrict__ Cb, float* __restrict__ h, f16* __restrict__ h16)
{
    int idx = blockIdx.x * 256 + threadIdx.x;
    if (idx >= N * (H / 2)) return;
    const int node = idx >> 7;
    const int j = (idx & 127) << 1;
    const int p = invt[node];
    const f16* base = (p >= 0) ? V + (size_t)p * G4 : U + (size_t)node * G4;
    const f16* zr = Zr + (size_t)node * G4;

    float g0[4], g1[4];
    #pragma unroll
    for (int g = 0; g < 4; ++g) {
        const int off = g * 256 + j;
        half2v xv = *(const half2v*)&base[off];
        half2v zv = *(const half2v*)&zr[off];
        float2 bi = *(const float2*)&b_ih[off];
        float2 bh = *(const float2*)&b_hh[off];
        g0[g] = (float)xv[0] + (float)zv[0] + bi.x + bh.x;
        g1[g] = (float)xv[1] + (float)zv[1] + bi.y + bh.y;
    }
    const size_t cidx = (size_t)node * H + j;
    float2 c = *(float2*)&Cb[cidx];
    auto sig = [](float x) { return 1.f / (1.f + __expf(-x)); };
    float c0 = sig(g0[1]) * c.x + sig(g0[0]) * tanhf(g0[2]);
    float c1 = sig(g1[1]) * c.y + sig(g1[0]) * tanhf(g1[2]);
    float h0 = sig(g0[3]) * tanhf(c0);
    float h1 = sig(g1[3]) * tanhf(c1);
    *(float2*)&Cb[cidx] = make_float2(c0, c1);
    *(float2*)&h[cidx]  = make_float2(h0, h1);
    half2v hh = { (f16)h0, (f16)h1 };
    *(half2v*)&h16[(size_t)node * H + j] = hh;
}

extern "C" void kernel_launch(void* const* d_in, const int* in_sizes, int n_in,
                              void* d_out, int out_size, void* d_ws, size_t ws_size,
                              hipStream_t stream)
{
    const float* A_all = (const float*)d_in[0];
    const float* nf    = (const float*)d_in[1];
    const int*   mask  = (const int*)  d_in[2];
    const float* w0    = (const float*)d_in[3];
    const float* w1    = (const float*)d_in[4];
    const float* W_ih  = (const float*)d_in[5];
    const float* W_hh  = (const float*)d_in[6];
    const float* b_ih  = (const float*)d_in[7];
    const float* b_hh  = (const float*)d_in[8];
    float* h = (float*)d_out;

    char* wp = (char*)d_ws;
    auto alloc = [&](size_t bytes) { char* p = wp; wp += (bytes + 255) & ~(size_t)255; return p; };
    f16*   nf16  = (f16*)alloc((size_t)NP * F * 2);
    f16*   w0T   = (f16*)alloc((size_t)F * F * 2);
    f16*   w1T   = (f16*)alloc((size_t)F * F * 2);
    f16*   Wih16 = (f16*)alloc((size_t)G4 * F * 2);
    f16*   Whh16 = (f16*)alloc((size_t)G4 * H * 2);
    f16*   Y0h   = (f16*)alloc((size_t)NP * F * 2);
    f16*   Y1h   = (f16*)alloc((size_t)NP * F * 2);
    f16*   Uh    = (f16*)alloc((size_t)NP * G4 * 2);
    f16*   GT    = (f16*)alloc((size_t)T * F * M * 2);
    f16*   Z1b   = (f16*)alloc((size_t)T * M * F * 2);
    f16*   Z2T   = (f16*)alloc((size_t)T * F * M * 2);
    f16*   Z3b   = (f16*)alloc((size_t)T * M * F * 2);
    f16*   Vb    = (f16*)alloc((size_t)4 * M * G4 * 2);   // 4-step chunks
    f16*   ZTb   = (f16*)alloc((size_t)NP * G4 * 2);
    float* Cb    = (float*)alloc((size_t)N * H * 4);
    f16*   h16   = (f16*)alloc((size_t)NP * H * 2);
    int*   inv   = (int*)alloc((size_t)T * N * 4);

    hipMemsetAsync(Cb,  0,    (size_t)N * H * 4,  stream);
    hipMemsetAsync(h16, 0,    (size_t)NP * H * 2, stream);
    hipMemsetAsync(nf16,0,    (size_t)NP * F * 2, stream);
    hipMemsetAsync(inv, 0xFF, (size_t)T * N * 4,  stream);

    build_inv<<<(T * M + 255) / 256, 256, 0, stream>>>(mask, inv);
    cvt_f16 <<<((long long)N * F / 4 + 255) / 256, 256, 0, stream>>>(nf, nf16, (long long)N * F);
    cvtT_f16<<<(F * F + 255) / 256, 256, 0, stream>>>(w0, w0T, F, F);
    cvtT_f16<<<(F * F + 255) / 256, 256, 0, stream>>>(w1, w1T, F, F);
    cvt_f16 <<<((long long)G4 * F / 4 + 255) / 256, 256, 0, stream>>>(W_ih, Wih16, (long long)G4 * F);
    cvt_f16 <<<((long long)G4 * H / 4 + 255) / 256, 256, 0, stream>>>(W_hh, Whh16, (long long)G4 * H);

    // Y0 = nf @ w0 ; Y1 = Y0 @ w1 ; U = Y1 @ W_ih^T   (all f16 out)
    gemm16<false,false,1><<<dim3(F / 128,  NP / 128, 1), 256, 0, stream>>>(nf16, 0, w0T,   0, Y0h, 0, F, F,  NP, 0);
    gemm16<false,false,1><<<dim3(F / 128,  NP / 128, 1), 256, 0, stream>>>(Y0h,  0, w1T,   0, Y1h, 0, F, F,  NP, 0);
    gemm16<false,false,1><<<dim3(G4 / 128, NP / 128, 1), 256, 0, stream>>>(Y1h,  0, Wih16, 0, Uh,  0, F, G4, NP, 0);

    gather_T<<<dim3(M / 64, T), 256, 0, stream>>>(Y0h, mask, GT);

    const long long sAmm = (long long)M * M;
    const long long sFM  = (long long)F * M;
    const long long sMF  = (long long)M * F;
    // Z1 = relu(A_t @ G_t)        : A f32, B = GT, out f16 [M][F]
    gemm16<true, true, 1><<<dim3(2, 16, T), 256, 0, stream>>>(A_all, sAmm, GT,    sFM, Z1b, sMF, M, F, M, 0);
    // Z2T = (Z1 @ w1)^T           : out f16 [F][M]
    gemm16<false,false,2><<<dim3(2, 16, T), 256, 0, stream>>>(Z1b,  sMF,  w1T,   0,   Z2T, sFM, F, F, M, M);
    // Z3 = relu(A_t @ Z2)         : B = Z2T, out f16 [M][F]
    gemm16<true, true, 1><<<dim3(2, 16, T), 256, 0, stream>>>(A_all, sAmm, Z2T,   sFM, Z3b, sMF, M, F, M, 0);

    for (int t = 0; t < T; ++t) {
        if ((t & 3) == 0) {  // V[t..t+3] = Z3_t @ W_ih^T  (4-step batch)
            gemm16<false,false,1><<<dim3(G4 / 128, M / 128, 4), 256, 0, stream>>>(
                Z3b + (size_t)t * M * F, sMF, Wih16, 0, Vb, (long long)M * G4, F, G4, M, 0);
        }
        // ZT = h @ W_hh^T  (sequential dependency)
        gemm16<false,false,1><<<dim3(G4 / 128, NP / 128, 1), 256, 0, stream>>>(
            h16, 0, Whh16, 0, ZTb, 0, H, G4, NP, 0);
        lstm_cell<<<(N * (H / 2) + 255) / 256, 256, 0, stream>>>(
            Uh, Vb + (size_t)(t & 3) * M * G4, ZTb, inv + (size_t)t * N,
            b_ih, b_hh, Cb, h, h16);
    }
}

// Round 3
// 792.676 us; speedup vs baseline: 4.8574x; 1.0298x over previous
//
#include <hip/hip_runtime.h>
#include <cstdint>
#include <cstddef>

#pragma clang diagnostic ignored "-Waddress-space-conversion"

constexpr int T  = 16;
constexpr int N  = 10000;
constexpr int M  = 2048;
constexpr int F  = 256;
constexpr int H  = 256;
constexpr int G4 = 1024;
constexpr int NP = 10112;   // N padded to multiple of 128

typedef _Float16 f16;
using half8  = __attribute__((ext_vector_type(8))) f16;
using half4  = __attribute__((ext_vector_type(4))) f16;
using half2v = __attribute__((ext_vector_type(2))) f16;
using f32x4  = __attribute__((ext_vector_type(4))) float;

typedef __attribute__((address_space(1))) const void gas_t;
typedef __attribute__((address_space(3))) void las_t;

__device__ __forceinline__ void gl_lds16(const f16* g, f16* l) {
    __builtin_amdgcn_global_load_lds((gas_t*)g, (las_t*)l, 16, 0, 0);
}

// ---------------------------------------------------------------------------
// C[m][n] (+relu) = A[m][k] * B[n][k]   (both operands k-contiguous)
// A: f32 (AF32, reg-staged+converted) or f16 (global_load_lds).
// OMODE: 1 = f16 row-major, 2 = f16 transposed (C^T [Nn][ldct])
// ---------------------------------------------------------------------------
template<bool AF32, bool RELU, int OMODE>
__global__ __launch_bounds__(256, 2)
void gemm16(const void* __restrict__ Ag, long long sA,
            const f16*  __restrict__ Bg, long long sB,
            void*       __restrict__ Cg, long long sC,
            int Kk, int Nn, int Mvalid, int ldct)
{
    __shared__ f16 Als[2][128 * 32];
    __shared__ f16 Bls[2][128 * 32];

    const int tid  = threadIdx.x;
    const int lane = tid & 63;
    const int w    = tid >> 6;
    const int wm   = w >> 1, wn = w & 1;
    const int m0   = blockIdx.y * 128, n0 = blockIdx.x * 128;
    const int z    = blockIdx.z;

    const f16* Bt = Bg + (size_t)z * sB;
    const int srow = lane >> 2;
    const int scol = (lane & 3) * 8;

    f32x4 acc[4][4] = {};

    auto stage = [&](int buf, int kt) {
        const int k0 = kt * 32;
        #pragma unroll
        for (int c = 0; c < 2; ++c) {
            const int brow = w * 32 + c * 16;
            gl_lds16(Bt + (size_t)(n0 + brow + srow) * Kk + k0 + scol,
                     &Bls[buf][brow * 32]);
        }
        if constexpr (AF32) {
            const float* Af = (const float*)Ag + (size_t)z * sA;
            #pragma unroll
            for (int p = 0; p < 4; ++p) {
                const int flat = p * 1024 + tid * 4;
                const int r = flat >> 5, cc = flat & 31;
                float4 v = *(const float4*)&Af[(size_t)(m0 + r) * Kk + k0 + cc];
                half4 hv = { (f16)v.x, (f16)v.y, (f16)v.z, (f16)v.w };
                *(half4*)&Als[buf][r * 32 + cc] = hv;
            }
        } else {
            const f16* Af = (const f16*)Ag + (size_t)z * sA;
            #pragma unroll
            for (int c = 0; c < 2; ++c) {
                const int arow = w * 32 + c * 16;
                gl_lds16(Af + (size_t)(m0 + arow + srow) * Kk + k0 + scol,
                         &Als[buf][arow * 32]);
            }
        }
    };

    const int nk = Kk >> 5;
    stage(0, 0);
    int cur = 0;
    const int fr = lane & 15, fg = lane >> 4;

    for (int kt = 0; kt < nk; ++kt) {
        __syncthreads();
        if (kt + 1 < nk) stage(cur ^ 1, kt + 1);

        half8 a[4], b[4];
        #pragma unroll
        for (int i = 0; i < 4; ++i)
            a[i] = *(const half8*)&Als[cur][(wm * 64 + i * 16 + fr) * 32 + fg * 8];
        #pragma unroll
        for (int j = 0; j < 4; ++j)
            b[j] = *(const half8*)&Bls[cur][(wn * 64 + j * 16 + fr) * 32 + fg * 8];
        #pragma unroll
        for (int i = 0; i < 4; ++i)
            #pragma unroll
            for (int j = 0; j < 4; ++j)
                acc[i][j] = __builtin_amdgcn_mfma_f32_16x16x32_f16(a[i], b[j], acc[i][j], 0, 0, 0);
        cur ^= 1;
    }

    #pragma unroll
    for (int i = 0; i < 4; ++i) {
        const int gmb = m0 + wm * 64 + i * 16 + fg * 4;
        #pragma unroll
        for (int j = 0; j < 4; ++j) {
            const int gn = n0 + wn * 64 + j * 16 + fr;
            f32x4 v = acc[i][j];
            if (RELU) {
                v[0] = fmaxf(v[0], 0.f); v[1] = fmaxf(v[1], 0.f);
                v[2] = fmaxf(v[2], 0.f); v[3] = fmaxf(v[3], 0.f);
            }
            if constexpr (OMODE == 1) {
                f16* Ch = (f16*)Cg + (size_t)z * sC;
                #pragma unroll
                for (int r = 0; r < 4; ++r)
                    if (gmb + r < Mvalid) Ch[(size_t)(gmb + r) * Nn + gn] = (f16)v[r];
            } else {
                f16* Ct = (f16*)Cg + (size_t)z * sC;
                half4 hv = { (f16)v[0], (f16)v[1], (f16)v[2], (f16)v[3] };
                if (gmb + 3 < Mvalid) *(half4*)&Ct[(size_t)gn * ldct + gmb] = hv;
            }
        }
    }
}

// ---------------------------------------------------------------------------
// Fused recurrent step: z = h16 @ Whh_perm^T (+U/V +bsum) -> gates -> c,h update.
// Gate-interleaved permuted layout: permuted col c64*64 + g*16 + r == gate g of
// unit u = c64*16 + r, so thread fragment j == gate j of ONE unit (no x-lane).
// ---------------------------------------------------------------------------
__global__ __launch_bounds__(256, 2)
void gemm_lstm(const f16* __restrict__ h16, const f16* __restrict__ Whh,
               const f16* __restrict__ U, const f16* __restrict__ V,
               const int* __restrict__ invt, const float* __restrict__ bsum,
               float* __restrict__ Cb, f16* __restrict__ h16_out,
               float* __restrict__ hout)
{
    __shared__ f16 Als[2][128 * 32];
    __shared__ f16 Bls[2][128 * 32];

    const int tid  = threadIdx.x;
    const int lane = tid & 63;
    const int w    = tid >> 6;
    const int wm   = w >> 1, wn = w & 1;
    const int m0   = blockIdx.y * 128, n0 = blockIdx.x * 128;

    const int srow = lane >> 2;
    const int scol = (lane & 3) * 8;

    f32x4 acc[4][4] = {};

    auto stage = [&](int buf, int kt) {
        const int k0 = kt * 32;
        #pragma unroll
        for (int c = 0; c < 2; ++c) {
            const int row = w * 32 + c * 16;
            gl_lds16(Whh + (size_t)(n0 + row + srow) * H + k0 + scol, &Bls[buf][row * 32]);
            gl_lds16(h16 + (size_t)(m0 + row + srow) * H + k0 + scol, &Als[buf][row * 32]);
        }
    };

    stage(0, 0);
    int cur = 0;
    const int fr = lane & 15, fg = lane >> 4;

    for (int kt = 0; kt < H / 32; ++kt) {
        __syncthreads();
        if (kt + 1 < H / 32) stage(cur ^ 1, kt + 1);
        half8 a[4], b[4];
        #pragma unroll
        for (int i = 0; i < 4; ++i)
            a[i] = *(const half8*)&Als[cur][(wm * 64 + i * 16 + fr) * 32 + fg * 8];
        #pragma unroll
        for (int j = 0; j < 4; ++j)
            b[j] = *(const half8*)&Bls[cur][(wn * 64 + j * 16 + fr) * 32 + fg * 8];
        #pragma unroll
        for (int i = 0; i < 4; ++i)
            #pragma unroll
            for (int j = 0; j < 4; ++j)
                acc[i][j] = __builtin_amdgcn_mfma_f32_16x16x32_f16(a[i], b[j], acc[i][j], 0, 0, 0);
        cur ^= 1;
    }

    // epilogue: thread owns unit u, gates j=0..3, 16 rows
    const int u = ((n0 >> 6) + wn) * 16 + fr;
    const int colbase = n0 + wn * 64 + fr;
    const float b0 = bsum[colbase], b1 = bsum[colbase + 16],
                b2 = bsum[colbase + 32], b3 = bsum[colbase + 48];
    auto sig = [](float x) { return 1.f / (1.f + __expf(-x)); };

    #pragma unroll
    for (int i = 0; i < 4; ++i) {
        const int nodeb = m0 + wm * 64 + i * 16 + fg * 4;
        #pragma unroll
        for (int r = 0; r < 4; ++r) {
            const int node = nodeb + r;
            if (node >= N) continue;
            const int p = invt[node];
            const f16* xb = (p >= 0) ? V + (size_t)p * G4 : U + (size_t)node * G4;
            const float zi = acc[i][0][r] + (float)xb[colbase]      + b0;
            const float zf = acc[i][1][r] + (float)xb[colbase + 16] + b1;
            const float zg = acc[i][2][r] + (float)xb[colbase + 32] + b2;
            const float zo = acc[i][3][r] + (float)xb[colbase + 48] + b3;
            const size_t ci = (size_t)node * H + u;
            const float c = sig(zf) * Cb[ci] + sig(zi) * tanhf(zg);
            Cb[ci] = c;
            const float hv = sig(zo) * tanhf(c);
            h16_out[ci] = (f16)hv;
            if (hout) hout[ci] = hv;
        }
    }
}

// GT[t][f][p] = Y0h[mask[t][p]][f]
__global__ __launch_bounds__(256)
void gather_T(const f16* __restrict__ Y0h, const int* __restrict__ mask,
              f16* __restrict__ GT)
{
    __shared__ f16 tile[64][F + 8];
    const int t = blockIdx.y, p0 = blockIdx.x * 64;
    const int tid = threadIdx.x;
    const int pr = tid >> 2;
    const int fc = (tid & 3) * 8;

    const int row = mask[t * M + p0 + pr];
    const f16* src = Y0h + (size_t)row * F;
    #pragma unroll
    for (int it = 0; it < 8; ++it) {
        const int f = it * 32 + fc;
        *(half8*)&tile[pr][f] = *(const half8*)&src[f];
    }
    __syncthreads();

    f16* dst = GT + ((size_t)t * F + tid) * M + p0;
    #pragma unroll
    for (int pc = 0; pc < 64; pc += 8) {
        half8 v;
        #pragma unroll
        for (int r = 0; r < 8; ++r) v[r] = tile[pc + r][tid];
        *(half8*)&dst[pc] = v;
    }
}

__global__ void cvt_f16(const float* __restrict__ s, f16* __restrict__ d, long long n)
{
    long long base = ((long long)blockIdx.x * blockDim.x + threadIdx.x) * 4;
    if (base + 3 < n) {
        float4 v = *(const float4*)&s[base];
        half4 hv = { (f16)v.x, (f16)v.y, (f16)v.z, (f16)v.w };
        *(half4*)&d[base] = hv;
    } else {
        for (long long k = base; k < n; ++k) d[k] = (f16)s[k];
    }
}

__global__ void cvtT_f16(const float* __restrict__ s, f16* __restrict__ d, int R, int C)
{
    int i = blockIdx.x * 256 + threadIdx.x;
    if (i >= R * C) return;
    int r = i % R, c = i / R;
    d[(size_t)c * R + r] = (f16)s[(size_t)r * C + c];
}

// Wperm[pcol][k] = W[gate*256 + c64*16 + r][k], pcol = c64*64 + gate*16 + r
__global__ void permW(const float* __restrict__ s, f16* __restrict__ d, int K)
{
    const int pcol = blockIdx.x;
    const int c64 = pcol >> 6, within = pcol & 63, gate = within >> 4, r = within & 15;
    const int srow = gate * 256 + c64 * 16 + r;
    const float* sp = s + (size_t)srow * K;
    f16* dp = d + (size_t)pcol * K;
    const int k = threadIdx.x * 4;
    float4 v = *(const float4*)&sp[k];
    half4 hv = { (f16)v.x, (f16)v.y, (f16)v.z, (f16)v.w };
    *(half4*)&dp[k] = hv;
}

__global__ void bias_perm(const float* __restrict__ bi, const float* __restrict__ bh,
                          float* __restrict__ bsum)
{
    const int pcol = blockIdx.x * 256 + threadIdx.x;
    if (pcol >= G4) return;
    const int c64 = pcol >> 6, within = pcol & 63, gate = within >> 4, r = within & 15;
    const int srow = gate * 256 + c64 * 16 + r;
    bsum[pcol] = bi[srow] + bh[srow];
}

__global__ void build_inv(const int* __restrict__ mask, int* __restrict__ inv)
{
    int i = blockIdx.x * blockDim.x + threadIdx.x;
    if (i >= T * M) return;
    int t = i / M;
    inv[(size_t)t * N + mask[i]] = i % M;
}

extern "C" void kernel_launch(void* const* d_in, const int* in_sizes, int n_in,
                              void* d_out, int out_size, void* d_ws, size_t ws_size,
                              hipStream_t stream)
{
    const float* A_all = (const float*)d_in[0];
    const float* nf    = (const float*)d_in[1];
    const int*   mask  = (const int*)  d_in[2];
    const float* w0    = (const float*)d_in[3];
    const float* w1    = (const float*)d_in[4];
    const float* W_ih  = (const float*)d_in[5];
    const float* W_hh  = (const float*)d_in[6];
    const float* b_ih  = (const float*)d_in[7];
    const float* b_hh  = (const float*)d_in[8];
    float* h = (float*)d_out;

    char* wp = (char*)d_ws;
    auto alloc = [&](size_t bytes) { char* p = wp; wp += (bytes + 255) & ~(size_t)255; return p; };
    f16*   nf16  = (f16*)alloc((size_t)NP * F * 2);
    f16*   w0T   = (f16*)alloc((size_t)F * F * 2);
    f16*   w1T   = (f16*)alloc((size_t)F * F * 2);
    f16*   Wih16 = (f16*)alloc((size_t)G4 * F * 2);   // permuted rows
    f16*   Whh16 = (f16*)alloc((size_t)G4 * H * 2);   // permuted rows
    float* bsum  = (float*)alloc((size_t)G4 * 4);
    f16*   Y0h   = (f16*)alloc((size_t)NP * F * 2);
    f16*   Y1h   = (f16*)alloc((size_t)NP * F * 2);
    f16*   Uh    = (f16*)alloc((size_t)NP * G4 * 2);  // permuted cols
    f16*   GT    = (f16*)alloc((size_t)T * F * M * 2);
    f16*   Z1b   = (f16*)alloc((size_t)T * M * F * 2);
    f16*   Z2T   = (f16*)alloc((size_t)T * F * M * 2);
    f16*   Z3b   = (f16*)alloc((size_t)T * M * F * 2);
    f16*   Vb    = (f16*)alloc((size_t)4 * M * G4 * 2);
    float* Cb    = (float*)alloc((size_t)N * H * 4);
    f16*   h16   = (f16*)alloc((size_t)NP * H * 2);
    int*   inv   = (int*)alloc((size_t)T * N * 4);

    hipMemsetAsync(Cb,  0,    (size_t)N * H * 4,  stream);
    hipMemsetAsync(h16, 0,    (size_t)NP * H * 2, stream);
    hipMemsetAsync(nf16,0,    (size_t)NP * F * 2, stream);
    hipMemsetAsync(inv, 0xFF, (size_t)T * N * 4,  stream);

    build_inv<<<(T * M + 255) / 256, 256, 0, stream>>>(mask, inv);
    cvt_f16 <<<((long long)N * F / 4 + 255) / 256, 256, 0, stream>>>(nf, nf16, (long long)N * F);
    cvtT_f16<<<(F * F + 255) / 256, 256, 0, stream>>>(w0, w0T, F, F);
    cvtT_f16<<<(F * F + 255) / 256, 256, 0, stream>>>(w1, w1T, F, F);
    permW<<<G4, 64, 0, stream>>>(W_ih, Wih16, F);
    permW<<<G4, 64, 0, stream>>>(W_hh, Whh16, H);
    bias_perm<<<(G4 + 255) / 256, 256, 0, stream>>>(b_ih, b_hh, bsum);

    gemm16<false,false,1><<<dim3(F / 128,  NP / 128, 1), 256, 0, stream>>>(nf16, 0, w0T,   0, Y0h, 0, F, F,  NP, 0);
    gemm16<false,false,1><<<dim3(F / 128,  NP / 128, 1), 256, 0, stream>>>(Y0h,  0, w1T,   0, Y1h, 0, F, F,  NP, 0);
    gemm16<false,false,1><<<dim3(G4 / 128, NP / 128, 1), 256, 0, stream>>>(Y1h,  0, Wih16, 0, Uh,  0, F, G4, NP, 0);

    gather_T<<<dim3(M / 64, T), 256, 0, stream>>>(Y0h, mask, GT);

    const long long sAmm = (long long)M * M;
    const long long sFM  = (long long)F * M;
    const long long sMF  = (long long)M * F;
    gemm16<true, true, 1><<<dim3(2, 16, T), 256, 0, stream>>>(A_all, sAmm, GT,  sFM, Z1b, sMF, M, F, M, 0);
    gemm16<false,false,2><<<dim3(2, 16, T), 256, 0, stream>>>(Z1b,  sMF,  w1T, 0,   Z2T, sFM, F, F, M, M);
    gemm16<true, true, 1><<<dim3(2, 16, T), 256, 0, stream>>>(A_all, sAmm, Z2T, sFM, Z3b, sMF, M, F, M, 0);

    for (int t = 0; t < T; ++t) {
        if ((t & 3) == 0) {
            gemm16<false,false,1><<<dim3(G4 / 128, M / 128, 4), 256, 0, stream>>>(
                Z3b + (size_t)t * M * F, sMF, Wih16, 0, Vb, (long long)M * G4, F, G4, M, 0);
        }
        gemm_lstm<<<dim3(G4 / 128, NP / 128, 1), 256, 0, stream>>>(
            h16, Whh16, Uh, Vb + (size_t)(t & 3) * M * G4, inv + (size_t)t * N,
            bsum, Cb, h16, (t == T - 1) ? h : nullptr);
    }
}